// Round 10
// baseline (833.521 us; speedup 1.0000x reference)
//
#include <hip/hip_runtime.h>

typedef unsigned short u16;
typedef __attribute__((ext_vector_type(8))) short bh8;
typedef __attribute__((ext_vector_type(4))) float fx4;

__device__ __forceinline__ u16 f2b(float f){
  unsigned int u = __float_as_uint(f);
  u += 0x7fffu + ((u>>16)&1u);
  return (u16)(u>>16);
}
__device__ __forceinline__ float b2f(u16 h){
  return __uint_as_float(((unsigned int)h)<<16);
}
__device__ __forceinline__ bh8 ldf(const u16* p){
  return *(const bh8*)p;
}
#define MFMA(a,b,c) __builtin_amdgcn_mfma_f32_16x16x32_bf16((a),(b),(c),0,0,0)

// ---------------- ws (bf16 weight cache) layout, u16 offsets ----------------
static const long OFF_W1 = 0;       // [32][64][136]
static const long OFF_W2 = 278528;  // [32][64][72]
static const long OFF_WJ = 425984;  // [256][136] (rows>=248 zero)
static const long OFF_PI = 460800;  // [3][64][72]
static const long OFF_QK = 474624;  // [3][192][72]
static const long OFF_AO = 516096;  // [3][64][72]
static const long OFF_PO = 529920;  // [3][64][72]
static const long WS_U16 = 543744;  // 1,087,488 bytes needed

__global__ __launch_bounds__(256) void conv_kernel(
  const float* __restrict__ w1, const float* __restrict__ w2,
  const float* __restrict__ wj, const float* __restrict__ pi,
  const float* __restrict__ qk, const float* __restrict__ ao,
  const float* __restrict__ po, u16* __restrict__ ws)
{
  const int stride = gridDim.x*blockDim.x;
  const int g0 = blockIdx.x*blockDim.x + threadIdx.x;
  for (int i=g0;i<2048*136;i+=stride){ int r=i/136,c=i-r*136; ws[OFF_W1+i]= (c<128)? f2b(w1[(long)r*128+c]) : (u16)0; }
  for (int i=g0;i<2048*72;i+=stride){ int r=i/72,c=i-r*72; ws[OFF_W2+i]= (c<64)? f2b(w2[(long)(r<<6)+c]) : (u16)0; }
  for (int i=g0;i<256*136;i+=stride){ int r=i/136,c=i-r*136; ws[OFF_WJ+i]= (c<128&&r<248)? f2b(wj[(long)(r<<7)+c]) : (u16)0; }
  for (int i=g0;i<192*72;i+=stride){ int r=i/72,c=i-r*72; ws[OFF_PI+i]= (c<64)? f2b(pi[(r<<6)+c]) : (u16)0; }
  for (int i=g0;i<576*72;i+=stride){ int r=i/72,c=i-r*72; ws[OFF_QK+i]= (c<64)? f2b(qk[(r<<6)+c]) : (u16)0; }
  for (int i=g0;i<192*72;i+=stride){ int r=i/72,c=i-r*72; ws[OFF_AO+i]= (c<64)? f2b(ao[(r<<6)+c]) : (u16)0; }
  for (int i=g0;i<192*72;i+=stride){ int r=i/72,c=i-r*72; ws[OFF_PO+i]= (c<64)? f2b(po[(r<<6)+c]) : (u16)0; }
}

// ================= Kernel 1: encoder (obs -> link, joint) — unchanged (proven) =================
struct __align__(16) SMem1 {
  u16 obs_l[16][136];
  u16 wa[64][136];
  u16 wb[64][72];
  u16 hb[16][72];
};

template<bool PRE>
__global__ __launch_bounds__(256) void enc_kernel(
  const float* __restrict__ obs, const float* __restrict__ w1,
  const float* __restrict__ b1, const float* __restrict__ w2,
  const float* __restrict__ b2, const float* __restrict__ wj,
  const float* __restrict__ bj, const u16* __restrict__ wsw,
  float* __restrict__ dout)
{
  __shared__ SMem1 s;
  const int tid = threadIdx.x;
  const int wave = tid>>6, lane = tid&63;
  const int g = lane>>4, cc = lane&15;
  const long bb = (long)blockIdx.x*16;

  for (int i=tid;i<16*128;i+=256){ int r=i>>7,c=i&127; s.obs_l[r][c]=f2b(obs[(bb+r)*128+c]); }

  for (int l=0;l<32;l++){
    if (PRE){
      const u16* s1 = wsw + OFF_W1 + (long)l*8704;
      for (int i=tid*8;i<8704;i+=2048) *(bh8*)(&s.wa[0][0]+i) = *(const bh8*)(s1+i);
      const u16* s2 = wsw + OFF_W2 + (long)l*4608;
      for (int i=tid*8;i<4608;i+=2048) *(bh8*)(&s.wb[0][0]+i) = *(const bh8*)(s2+i);
    } else {
      for (int i=tid;i<64*128;i+=256){ s.wa[i>>7][i&127]=f2b(w1[(long)l*8192+i]); }
      for (int i=tid;i<64*64;i+=256){ s.wb[i>>6][i&63]=f2b(w2[(long)l*4096+i]); }
    }
    __syncthreads();
    { // h = elu(obs @ W1[l]^T + b1[l])
      fx4 acc = {0.f,0.f,0.f,0.f};
      #pragma unroll
      for (int ks=0;ks<4;ks++)
        acc = MFMA(ldf(&s.obs_l[cc][ks*32+g*8]), ldf(&s.wa[wave*16+cc][ks*32+g*8]), acc);
      int col = wave*16+cc;
      float bias = b1[l*64+col];
      #pragma unroll
      for (int r=0;r<4;r++){
        float v = acc[r]+bias;
        v = v>0.f ? v : expm1f(v);
        s.hb[g*4+r][col] = f2b(v);
      }
    }
    __syncthreads();
    { // link[l] = h @ W2[l]^T + b2[l]
      fx4 acc = {0.f,0.f,0.f,0.f};
      #pragma unroll
      for (int ks=0;ks<2;ks++)
        acc = MFMA(ldf(&s.hb[cc][ks*32+g*8]), ldf(&s.wb[wave*16+cc][ks*32+g*8]), acc);
      int col = wave*16+cc;
      float bias = b2[l*64+col];
      #pragma unroll
      for (int r=0;r<4;r++)
        dout[(bb+g*4+r)*2296 + l*64 + col] = acc[r]+bias;
    }
    __syncthreads();
  }
  // joint = obs @ Wj^T + bj  (248 outputs, 4 chunks of 64)
  for (int ci=0;ci<4;ci++){
    if (PRE){
      const u16* sj = wsw + OFF_WJ + (long)ci*8704;
      for (int i=tid*8;i<8704;i+=2048) *(bh8*)(&s.wa[0][0]+i) = *(const bh8*)(sj+i);
    } else {
      for (int i=tid;i<64*128;i+=256){
        int r=i>>7,c=i&127; int grow=ci*64+r;
        s.wa[r][c] = (grow<248)? f2b(wj[(long)grow*128+c]) : (u16)0;
      }
    }
    __syncthreads();
    fx4 acc={0.f,0.f,0.f,0.f};
    #pragma unroll
    for (int ks=0;ks<4;ks++)
      acc = MFMA(ldf(&s.obs_l[cc][ks*32+g*8]), ldf(&s.wa[wave*16+cc][ks*32+g*8]), acc);
    int ncol = ci*64 + wave*16 + cc;
    if (ncol<248){
      float bias = bj[ncol];
      #pragma unroll
      for (int r=0;r<4;r++)
        dout[(bb+g*4+r)*2296 + 2048 + ncol] = acc[r]+bias;
    }
    __syncthreads();
  }
}

// ========== Kernel 2: fused loop — 2 batches / 256 threads / SINGLE-STAGE qkv (bisect) ==========
struct __align__(16) SMem2 {
  float tokf[2][32][68];     // 17408 B  f32 tok state
  u16   tokb[2][32][72];     //  9216 B  bf16 mirror
  u16   xs[64*72];           //  9216 B  x, later o
  u16   qs[64*72];           //  9216 B  q, later o2
  u16   kk[64*72];           //  9216 B  k
  u16   vT[2][64][40];       // 10240 B  V transposed
  float joint[2][31][8];     //  1984 B
  union {
    u16 w[192*72];           // 27648 B  staged weights (qkv full 192 rows, like R8)
    u16 p[4][32][40];        // 10240 B  per-wave P tiles
  } u;
};
static_assert(sizeof(SMem2) <= 163840, "LDS overflow");

// 4-wave GEMM: one 16-row mtile per wave (rows wave*16+..., total 64 = 2 batches)
template<int NT, class EPI>
__device__ __forceinline__ void gemm4(const u16* A, const u16* W,
                                      int wave, int lane, EPI epi){
  const int g = lane>>4, cc = lane&15;
  const int row = wave*16 + cc;
  bh8 a0 = ldf(&A[row*72 + g*8]);
  bh8 a1 = ldf(&A[row*72 + 32 + g*8]);
  #pragma unroll
  for (int nt=0;nt<NT;nt++){
    bh8 b0 = ldf(&W[(nt*16+cc)*72 + g*8]);
    bh8 b1 = ldf(&W[(nt*16+cc)*72 + 32 + g*8]);
    fx4 acc = {0.f,0.f,0.f,0.f};
    acc = MFMA(a0,b0,acc);
    acc = MFMA(a1,b1,acc);
    epi(nt, wave, acc);
  }
}

template<bool PRE>
__device__ __forceinline__ void stageW(u16* dst, const u16* wsrc, const float* fsrc, int rows){
  if (PRE){
    const int n = rows*72;
    for (int i=threadIdx.x*8; i<n; i+=2048)
      *(bh8*)(dst+i) = *(const bh8*)(wsrc+i);
  } else {
    const int n = rows*64;
    for (int i=threadIdx.x; i<n; i+=256)
      dst[(i>>6)*72 + (i&63)] = f2b(fsrc[i]);
  }
}

template<bool PRE>
__global__ __launch_bounds__(256,1) void rodri_main(
  const float* __restrict__ rod_mix, const float* __restrict__ rod_theta_w,
  const float* __restrict__ rod_theta_b, const float* __restrict__ rod_gen,
  const float* __restrict__ rod_ln_g, const float* __restrict__ rod_ln_b,
  const float* __restrict__ jl_w, const float* __restrict__ jl_b,
  const float* __restrict__ proj_in_w, const float* __restrict__ proj_in_b,
  const float* __restrict__ qkv_w, const float* __restrict__ qkv_b,
  const float* __restrict__ attn_out_w, const float* __restrict__ attn_out_b,
  const float* __restrict__ proj_out_w, const float* __restrict__ proj_out_b,
  const float* __restrict__ attn_ln_g, const float* __restrict__ attn_ln_b,
  const u16* __restrict__ wsw, float* __restrict__ dout)
{
  __shared__ SMem2 s;
  const int tid = threadIdx.x;
  const int wave = tid>>6, lane = tid&63;
  const int g = lane>>4, cc = lane&15;
  const long bb = (long)blockIdx.x*2;

  // load state written by encoder
  for (int i=tid;i<2*2048;i+=256){
    int b=i>>11, r=i&2047;
    float v = dout[(bb+b)*2296 + r];
    s.tokf[b][r>>6][r&63] = v;
    s.tokb[b][r>>6][r&63] = f2b(v);
  }
  for (int i=tid;i<2*248;i+=256){
    int b=(i>=248); int r=i-b*248;
    s.joint[b][r>>3][r&7] = dout[(bb+b)*2296 + 2048 + r];
  }
  __syncthreads();

  for (int t=0;t<3;t++){
    // -------- Phase R: Rodrigues + rod LN — 256 threads, 4 per row, o = quarter --------
    {
      const int unit = tid>>2, o = tid&3;          // unit 0..63
      const int b = unit>>5, row = unit&31;
      float nv[16];
      if (row == 0){
        #pragma unroll
        for (int i=0;i<16;i++) nv[i] = s.tokf[b][0][o*16+i];
      } else {
        const int j = row-1;
        const long wj = (long)t*31 + j;
        const float* mixp = rod_mix + wj*16 + o*4;
        const float* thwp = rod_theta_w + wj*32 + o*8;
        const float* genp = rod_gen + wj*16;
        float a = rod_theta_b[wj*4+o];
        #pragma unroll
        for (int c8=0;c8<8;c8++) a += s.joint[b][j][c8]*thwp[c8];
        float sn = sinf(a), c1 = 1.f - cosf(a);
        const float m0 = mixp[0], m1 = mixp[1], m2 = mixp[2], m3 = mixp[3];
        float G[16];
        #pragma unroll
        for (int e=0;e<16;e++) G[e] = genp[e];
        #pragma unroll
        for (int z=0;z<4;z++){
          float fm[4], gf[4], gg[4];
          #pragma unroll
          for (int x=0;x<4;x++)
            fm[x] = m0*s.tokf[b][j][     x*4+z] + m1*s.tokf[b][j][16 + x*4+z]
                  + m2*s.tokf[b][j][32 + x*4+z] + m3*s.tokf[b][j][48 + x*4+z];
          #pragma unroll
          for (int x=0;x<4;x++)
            gf[x] = G[x*4+0]*fm[0] + G[x*4+1]*fm[1] + G[x*4+2]*fm[2] + G[x*4+3]*fm[3];
          #pragma unroll
          for (int x=0;x<4;x++)
            gg[x] = G[x*4+0]*gf[0] + G[x*4+1]*gf[1] + G[x*4+2]*gf[2] + G[x*4+3]*gf[3];
          #pragma unroll
          for (int x=0;x<4;x++)
            nv[x*4+z] = fm[x] + sn*gf[x] + c1*gg[x] + s.tokf[b][row][o*16+x*4+z];
        }
      }
      float sum=0.f, ssq=0.f;
      #pragma unroll
      for (int i=0;i<16;i++){ sum+=nv[i]; ssq+=nv[i]*nv[i]; }
      sum += __shfl_xor(sum,1); ssq += __shfl_xor(ssq,1);
      sum += __shfl_xor(sum,2); ssq += __shfl_xor(ssq,2);
      float mean = sum*(1.f/64.f);
      float var  = ssq*(1.f/64.f) - mean*mean;
      float rstd = rsqrtf(var + 1e-5f);
      const float* lng = rod_ln_g + ((long)t*32+row)*64 + o*16;
      const float* lnb = rod_ln_b + ((long)t*32+row)*64 + o*16;
      #pragma unroll
      for (int i=0;i<16;i++)
        nv[i] = (nv[i]-mean)*rstd*lng[i] + lnb[i];
      __syncthreads();   // all reads of old tok complete before overwrite
      #pragma unroll
      for (int i=0;i<16;i++){
        s.tokf[b][row][o*16+i] = nv[i];
        s.tokb[b][row][o*16+i] = f2b(nv[i]);
      }
    }
    __syncthreads();

    // -------- joint update: joint += child_flat @ jl_w^T + jl_b --------
    if (tid < 248){
      int j = tid>>3, c8 = tid&7;
      const float* wrow = jl_w + (((long)t*31 + j)*8 + c8)*64;
      float bias = jl_b[((long)t*31+j)*8 + c8];
      float a0=0.f,a1=0.f;
      for (int h=0;h<64;h++){
        float w = wrow[h];
        a0 += w*b2f(s.tokb[0][j+1][h]);
        a1 += w*b2f(s.tokb[1][j+1][h]);
      }
      s.joint[0][j][c8] += a0 + bias;
      s.joint[1][j][c8] += a1 + bias;
    }
    __syncthreads();

    // -------- proj_in: x = tok @ Wpi^T + b --------
    stageW<PRE>(s.u.w, wsw+OFF_PI+(long)t*4608, proj_in_w+(long)t*4096, 64);
    __syncthreads();
    {
      const float* bp = proj_in_b + (long)t*64;
      gemm4<4>(&s.tokb[0][0][0], s.u.w, wave, lane,
        [&](int nt,int mtile,const fx4& acc){
          int col = nt*16+cc;
          float bias = bp[col];
          #pragma unroll
          for (int r=0;r<4;r++){
            int rg = mtile*16+g*4+r;
            s.xs[rg*72+col] = f2b(acc[r]+bias);
          }
        });
    }
    __syncthreads();

    // -------- qkv: SINGLE 192-row stage (R8 flow) --------
    stageW<PRE>(s.u.w, wsw+OFF_QK+(long)t*13824, qkv_w+(long)t*12288, 192);
    __syncthreads();
    {
      const float* bq = qkv_b + (long)t*192;
      gemm4<12>(s.xs, s.u.w, wave, lane,
        [&](int nt,int mtile,const fx4& acc){
          int col = nt*16+cc;
          float bias = bq[col];
          #pragma unroll
          for (int r=0;r<4;r++){
            int rg = mtile*16+g*4+r;
            float v = acc[r]+bias;
            int b = rg>>5, l = rg&31;
            if (col<64)       s.qs[rg*72+col]      = f2b(v);
            else if (col<128) s.kk[rg*72+(col-64)] = f2b(v);
            else              s.vT[b][col-128][l]  = f2b(v);
          }
        });
    }
    __syncthreads();   // all waves done reading u.w before P clobbers it

    // -------- attention: 4 waves, wave -> (b = wave>>1, heads {wave&1, 2+(wave&1)}) --------
    {
      const int b = wave>>1;
      const u16* qb = s.qs + b*32*72;
      const u16* kb = s.kk + b*32*72;
      u16* ob = s.xs + b*32*72;
      bh8 z8 = {0,0,0,0,0,0,0,0};
      #pragma unroll
      for (int hh=0;hh<2;hh++){
        const int h = (wave&1) + 2*hh;
        bh8 qf[2], kf[2];
        #pragma unroll
        for (int it=0;it<2;it++)
          qf[it] = (g<2) ? ldf(&qb[(it*16+cc)*72 + h*16 + g*8]) : z8;
        #pragma unroll
        for (int jt=0;jt<2;jt++)
          kf[jt] = (g<2) ? ldf(&kb[(jt*16+cc)*72 + h*16 + g*8]) : z8;
        fx4 sacc[2][2];
        #pragma unroll
        for (int it=0;it<2;it++)
          #pragma unroll
          for (int jt=0;jt<2;jt++){
            fx4 z = {0.f,0.f,0.f,0.f};
            sacc[it][jt] = MFMA(qf[it], kf[jt], z);  // S[i][j]
          }
        float pn[2][2][4];
        #pragma unroll
        for (int it=0;it<2;it++)
          #pragma unroll
          for (int r=0;r<4;r++){
            float v0 = sacc[it][0][r], v1 = sacc[it][1][r];
            float m = fmaxf(v0,v1);
            #pragma unroll
            for (int msk=1; msk<16; msk<<=1) m = fmaxf(m, __shfl_xor(m,msk));
            float e0 = __expf((v0-m)*0.25f);
            float e1 = __expf((v1-m)*0.25f);
            float sm = e0+e1;
            #pragma unroll
            for (int msk=1; msk<16; msk<<=1) sm += __shfl_xor(sm,msk);
            float inv = 1.f/sm;
            pn[it][0][r]=e0*inv; pn[it][1][r]=e1*inv;
          }
        #pragma unroll
        for (int it=0;it<2;it++)
          #pragma unroll
          for (int jt=0;jt<2;jt++)
            #pragma unroll
            for (int r=0;r<4;r++)
              s.u.p[wave][it*16+g*4+r][jt*16+cc] = f2b(pn[it][jt][r]);
        // o[:, h*16:h*16+16] = P @ V   (exact K=32)
        bh8 vf = ldf(&s.vT[b][h*16+cc][g*8]);
        #pragma unroll
        for (int it=0;it<2;it++){
          bh8 pf = ldf(&s.u.p[wave][it*16+cc][g*8]);
          fx4 z = {0.f,0.f,0.f,0.f};
          fx4 oacc = MFMA(pf, vf, z);
          #pragma unroll
          for (int r=0;r<4;r++)
            ob[(it*16+g*4+r)*72 + h*16+cc] = f2b(oacc[r]);
        }
      }
    }
    __syncthreads();

    // -------- attn_out: o2 = o @ Wao^T + b --------
    stageW<PRE>(s.u.w, wsw+OFF_AO+(long)t*4608, attn_out_w+(long)t*4096, 64);
    __syncthreads();
    {
      const float* bo = attn_out_b + (long)t*64;
      gemm4<4>(s.xs, s.u.w, wave, lane,
        [&](int nt,int mtile,const fx4& acc){
          int col = nt*16+cc;
          float bias = bo[col];
          #pragma unroll
          for (int r=0;r<4;r++){
            int rg = mtile*16+g*4+r;
            s.qs[rg*72+col] = f2b(acc[r]+bias);
          }
        });
    }
    __syncthreads();

    // -------- proj_out + residual --------
    stageW<PRE>(s.u.w, wsw+OFF_PO+(long)t*4608, proj_out_w+(long)t*4096, 64);
    __syncthreads();
    {
      const float* bp2 = proj_out_b + (long)t*64;
      gemm4<4>(s.qs, s.u.w, wave, lane,
        [&](int nt,int mtile,const fx4& acc){
          int col = nt*16+cc;
          float bias = bp2[col];
          #pragma unroll
          for (int r=0;r<4;r++){
            int rg = mtile*16+g*4+r;
            int b = rg>>5, l = rg&31;
            s.tokf[b][l][col] += acc[r] + bias;
          }
        });
    }
    __syncthreads();

    // -------- attn LN — 256 threads, 4 per row --------
    {
      const int unit = tid>>2, o = tid&3;
      const int b = unit>>5, row = unit&31;
      float v[16];
      #pragma unroll
      for (int i=0;i<16;i++) v[i] = s.tokf[b][row][o*16+i];
      float sum=0.f, ssq=0.f;
      #pragma unroll
      for (int i=0;i<16;i++){ sum+=v[i]; ssq+=v[i]*v[i]; }
      sum += __shfl_xor(sum,1); ssq += __shfl_xor(ssq,1);
      sum += __shfl_xor(sum,2); ssq += __shfl_xor(ssq,2);
      float mean = sum*(1.f/64.f);
      float var  = ssq*(1.f/64.f) - mean*mean;
      float rstd = rsqrtf(var + 1e-5f);
      const float* lg = attn_ln_g + (long)t*64 + o*16;
      const float* lb = attn_ln_b + (long)t*64 + o*16;
      #pragma unroll
      for (int i=0;i<16;i++){
        float ov = (v[i]-mean)*rstd*lg[i] + lb[i];
        s.tokf[b][row][o*16+i] = ov;
        s.tokb[b][row][o*16+i] = f2b(ov);
      }
    }
    __syncthreads();
  } // t

  // -------- final output --------
  for (int i=tid;i<2*2048;i+=256){
    int b=i>>11, r=i&2047;
    dout[(bb+b)*2296 + r] = s.tokf[b][r>>6][r&63];
  }
  for (int i=tid;i<2*248;i+=256){
    int b=(i>=248); int r=i-b*248;
    dout[(bb+b)*2296 + 2048 + r] = s.joint[b][r>>3][r&7];
  }
}

extern "C" void kernel_launch(void* const* d_in, const int* in_sizes, int n_in,
                              void* d_out, int out_size, void* d_ws, size_t ws_size,
                              hipStream_t stream) {
  (void)in_sizes; (void)n_in; (void)out_size;
  float* out = (float*)d_out;
  u16* ws = (u16*)d_ws;
  const bool pre = (ws_size >= (size_t)WS_U16*2);

  if (pre){
    conv_kernel<<<dim3(512), dim3(256), 0, stream>>>(
      (const float*)d_in[1], (const float*)d_in[3], (const float*)d_in[5],
      (const float*)d_in[15], (const float*)d_in[17], (const float*)d_in[19],
      (const float*)d_in[21], ws);
    enc_kernel<true><<<dim3(512), dim3(256), 0, stream>>>(
      (const float*)d_in[0], (const float*)d_in[1], (const float*)d_in[2],
      (const float*)d_in[3], (const float*)d_in[4], (const float*)d_in[5],
      (const float*)d_in[6], ws, out);
    rodri_main<true><<<dim3(4096), dim3(256), 0, stream>>>(
      (const float*)d_in[7],  (const float*)d_in[8],  (const float*)d_in[9],
      (const float*)d_in[10], (const float*)d_in[11], (const float*)d_in[12],
      (const float*)d_in[13], (const float*)d_in[14], (const float*)d_in[15],
      (const float*)d_in[16], (const float*)d_in[17], (const float*)d_in[18],
      (const float*)d_in[19], (const float*)d_in[20], (const float*)d_in[21],
      (const float*)d_in[22], (const float*)d_in[23], (const float*)d_in[24],
      ws, out);
  } else {
    enc_kernel<false><<<dim3(512), dim3(256), 0, stream>>>(
      (const float*)d_in[0], (const float*)d_in[1], (const float*)d_in[2],
      (const float*)d_in[3], (const float*)d_in[4], (const float*)d_in[5],
      (const float*)d_in[6], ws, out);
    rodri_main<false><<<dim3(4096), dim3(256), 0, stream>>>(
      (const float*)d_in[7],  (const float*)d_in[8],  (const float*)d_in[9],
      (const float*)d_in[10], (const float*)d_in[11], (const float*)d_in[12],
      (const float*)d_in[13], (const float*)d_in[14], (const float*)d_in[15],
      (const float*)d_in[16], (const float*)d_in[17], (const float*)d_in[18],
      (const float*)d_in[19], (const float*)d_in[20], (const float*)d_in[21],
      (const float*)d_in[22], (const float*)d_in[23], (const float*)d_in[24],
      ws, out);
  }
}

// Round 13
// 485.639 us; speedup vs baseline: 1.7163x; 1.7163x over previous
//
#include <hip/hip_runtime.h>

typedef unsigned short u16;
typedef __attribute__((ext_vector_type(8))) short bh8;
typedef __attribute__((ext_vector_type(4))) float fx4;

__device__ __forceinline__ u16 f2b(float f){
  unsigned int u = __float_as_uint(f);
  u += 0x7fffu + ((u>>16)&1u);
  return (u16)(u>>16);
}
__device__ __forceinline__ float b2f(u16 h){
  return __uint_as_float(((unsigned int)h)<<16);
}
__device__ __forceinline__ bh8 ldf(const u16* p){
  return *(const bh8*)p;
}
#define MFMA(a,b,c) __builtin_amdgcn_mfma_f32_16x16x32_bf16((a),(b),(c),0,0,0)

// ---------------- ws (bf16 weight cache) layout, u16 offsets ----------------
static const long OFF_W1 = 0;       // [32][64][136]
static const long OFF_W2 = 278528;  // [32][64][72]
static const long OFF_WJ = 425984;  // [256][136] (rows>=248 zero)
static const long OFF_PI = 460800;  // [3][64][72]   (fallback use)
static const long OFF_QK = 474624;  // [3][192][72]  (fallback use)
static const long OFF_AO = 516096;  // [3][64][72]   (fallback use)
static const long OFF_PO = 529920;  // [3][64][72]   (fallback use)
static const long OFF_QP = 543744;  // [3][192][72]  folded qkv∘proj_in (bf16)
static const long OFF_OP = 585216;  // [3][64][72]   folded proj_out∘attn_out (bf16)
static const long OFF_BQ = 599040;  // [3][192] f32  folded qkv bias
static const long OFF_BO = 600192;  // [3][64]  f32  folded out bias
static const long WS_U16 = 600576;  // 1,201,152 bytes needed

__global__ __launch_bounds__(256) void conv_kernel(
  const float* __restrict__ w1, const float* __restrict__ w2,
  const float* __restrict__ wj,
  const float* __restrict__ pi, const float* __restrict__ pib,
  const float* __restrict__ qk, const float* __restrict__ qkb,
  const float* __restrict__ ao, const float* __restrict__ aob,
  const float* __restrict__ po, const float* __restrict__ pob,
  u16* __restrict__ ws)
{
  const int stride = gridDim.x*blockDim.x;
  const int g0 = blockIdx.x*blockDim.x + threadIdx.x;
  for (int i=g0;i<2048*136;i+=stride){ int r=i/136,c=i-r*136; ws[OFF_W1+i]= (c<128)? f2b(w1[(long)r*128+c]) : (u16)0; }
  for (int i=g0;i<2048*72;i+=stride){ int r=i/72,c=i-r*72; ws[OFF_W2+i]= (c<64)? f2b(w2[(long)(r<<6)+c]) : (u16)0; }
  for (int i=g0;i<256*136;i+=stride){ int r=i/136,c=i-r*136; ws[OFF_WJ+i]= (c<128&&r<248)? f2b(wj[(long)(r<<7)+c]) : (u16)0; }
  for (int i=g0;i<192*72;i+=stride){ int r=i/72,c=i-r*72; ws[OFF_PI+i]= (c<64)? f2b(pi[(r<<6)+c]) : (u16)0; }
  for (int i=g0;i<576*72;i+=stride){ int r=i/72,c=i-r*72; ws[OFF_QK+i]= (c<64)? f2b(qk[(r<<6)+c]) : (u16)0; }
  for (int i=g0;i<192*72;i+=stride){ int r=i/72,c=i-r*72; ws[OFF_AO+i]= (c<64)? f2b(ao[(r<<6)+c]) : (u16)0; }
  for (int i=g0;i<192*72;i+=stride){ int r=i/72,c=i-r*72; ws[OFF_PO+i]= (c<64)? f2b(po[(r<<6)+c]) : (u16)0; }

  // ---- folded qkv∘proj_in: Wqp[t][e][h] = sum_d qkv[t][e][d]*pi[t][d][h] ----
  for (int i=g0;i<3*192*64;i+=stride){
    int t=i/(192*64), rem=i-t*192*64, e=rem>>6, h=rem&63;
    const float* qw = qk + ((long)t*192+e)*64;
    const float* pw = pi + (long)t*4096 + h;
    float acc=0.f;
    #pragma unroll 8
    for (int d=0;d<64;d++) acc += qw[d]*pw[d*64];
    ws[OFF_QP + (long)t*13824 + e*72 + h] = f2b(acc);
  }
  // bq'[t][e] = qkv_b[t][e] + sum_d qkv[t][e][d]*pi_b[t][d]
  for (int i=g0;i<3*192;i+=stride){
    int t=i/192, e=i-t*192;
    const float* qw = qk + ((long)t*192+e)*64;
    const float* pb = pib + (long)t*64;
    float acc = qkb[(long)t*192+e];
    #pragma unroll 8
    for (int d=0;d<64;d++) acc += qw[d]*pb[d];
    ((float*)(ws+OFF_BQ))[i] = acc;
  }
  // ---- folded proj_out∘attn_out: Wop[t][n][d] = sum_e po[t][n][e]*ao[t][e][d] ----
  for (int i=g0;i<3*64*64;i+=stride){
    int t=i/(64*64), rem=i-t*64*64, n=rem>>6, d=rem&63;
    const float* pw = po + (long)t*4096 + (long)n*64;
    const float* aw = ao + (long)t*4096 + d;
    float acc=0.f;
    #pragma unroll 8
    for (int e=0;e<64;e++) acc += pw[e]*aw[e*64];
    ws[OFF_OP + (long)t*4608 + n*72 + d] = f2b(acc);
  }
  // bo'[t][n] = po_b[t][n] + sum_e ao_b[t][e]*po[t][n][e]
  for (int i=g0;i<3*64;i+=stride){
    int t=i/64, n=i-t*64;
    const float* pw = po + (long)t*4096 + (long)n*64;
    const float* ab = aob + (long)t*64;
    float acc = pob[(long)t*64+n];
    #pragma unroll 8
    for (int e=0;e<64;e++) acc += pw[e]*ab[e];
    ((float*)(ws+OFF_BO))[i] = acc;
  }
}

// ================= Kernel 1: encoder (obs -> link, joint) — unchanged (proven) =================
struct __align__(16) SMem1 {
  u16 obs_l[16][136];
  u16 wa[64][136];
  u16 wb[64][72];
  u16 hb[16][72];
};

template<bool PRE>
__global__ __launch_bounds__(256) void enc_kernel(
  const float* __restrict__ obs, const float* __restrict__ w1,
  const float* __restrict__ b1, const float* __restrict__ w2,
  const float* __restrict__ b2, const float* __restrict__ wj,
  const float* __restrict__ bj, const u16* __restrict__ wsw,
  float* __restrict__ dout)
{
  __shared__ SMem1 s;
  const int tid = threadIdx.x;
  const int wave = tid>>6, lane = tid&63;
  const int g = lane>>4, cc = lane&15;
  const long bb = (long)blockIdx.x*16;

  for (int i=tid;i<16*128;i+=256){ int r=i>>7,c=i&127; s.obs_l[r][c]=f2b(obs[(bb+r)*128+c]); }

  for (int l=0;l<32;l++){
    if (PRE){
      const u16* s1 = wsw + OFF_W1 + (long)l*8704;
      for (int i=tid*8;i<8704;i+=2048) *(bh8*)(&s.wa[0][0]+i) = *(const bh8*)(s1+i);
      const u16* s2 = wsw + OFF_W2 + (long)l*4608;
      for (int i=tid*8;i<4608;i+=2048) *(bh8*)(&s.wb[0][0]+i) = *(const bh8*)(s2+i);
    } else {
      for (int i=tid;i<64*128;i+=256){ s.wa[i>>7][i&127]=f2b(w1[(long)l*8192+i]); }
      for (int i=tid;i<64*64;i+=256){ s.wb[i>>6][i&63]=f2b(w2[(long)l*4096+i]); }
    }
    __syncthreads();
    { // h = elu(obs @ W1[l]^T + b1[l])
      fx4 acc = {0.f,0.f,0.f,0.f};
      #pragma unroll
      for (int ks=0;ks<4;ks++)
        acc = MFMA(ldf(&s.obs_l[cc][ks*32+g*8]), ldf(&s.wa[wave*16+cc][ks*32+g*8]), acc);
      int col = wave*16+cc;
      float bias = b1[l*64+col];
      #pragma unroll
      for (int r=0;r<4;r++){
        float v = acc[r]+bias;
        v = v>0.f ? v : expm1f(v);
        s.hb[g*4+r][col] = f2b(v);
      }
    }
    __syncthreads();
    { // link[l] = h @ W2[l]^T + b2[l]
      fx4 acc = {0.f,0.f,0.f,0.f};
      #pragma unroll
      for (int ks=0;ks<2;ks++)
        acc = MFMA(ldf(&s.hb[cc][ks*32+g*8]), ldf(&s.wb[wave*16+cc][ks*32+g*8]), acc);
      int col = wave*16+cc;
      float bias = b2[l*64+col];
      #pragma unroll
      for (int r=0;r<4;r++)
        dout[(bb+g*4+r)*2296 + l*64 + col] = acc[r]+bias;
    }
    __syncthreads();
  }
  // joint = obs @ Wj^T + bj  (248 outputs, 4 chunks of 64)
  for (int ci=0;ci<4;ci++){
    if (PRE){
      const u16* sj = wsw + OFF_WJ + (long)ci*8704;
      for (int i=tid*8;i<8704;i+=2048) *(bh8*)(&s.wa[0][0]+i) = *(const bh8*)(sj+i);
    } else {
      for (int i=tid;i<64*128;i+=256){
        int r=i>>7,c=i&127; int grow=ci*64+r;
        s.wa[r][c] = (grow<248)? f2b(wj[(long)grow*128+c]) : (u16)0;
      }
    }
    __syncthreads();
    fx4 acc={0.f,0.f,0.f,0.f};
    #pragma unroll
    for (int ks=0;ks<4;ks++)
      acc = MFMA(ldf(&s.obs_l[cc][ks*32+g*8]), ldf(&s.wa[wave*16+cc][ks*32+g*8]), acc);
    int ncol = ci*64 + wave*16 + cc;
    if (ncol<248){
      float bias = bj[ncol];
      #pragma unroll
      for (int r=0;r<4;r++)
        dout[(bb+g*4+r)*2296 + 2048 + ncol] = acc[r]+bias;
    }
    __syncthreads();
  }
}

// ================= Shared pieces for the 512-thread main kernels (R8-proven) =================
struct __align__(16) SMem2 {
  float tokf[4][32][68];     // f32 link/tok state (padded)
  u16   tokb[4][32][72];     // bf16 mirror for MFMA A-operand
  u16   xs[4*32*72];         // x, later o
  u16   qs[4*32*72];         // q, later o2
  u16   kk[4*32*72];         // k
  u16   vT[4][64][40];       // V transposed [d][l]
  float joint[4][31][8];
  union {
    u16 w[192*72];           // staged weight matrix (bf16, padded rows)
    u16 p[8][32][40];        // per-wave P tile (aliased; disjoint in time)
  } u;
};
static_assert(sizeof(SMem2) <= 163840, "LDS overflow");
// NOTE: 160KB LDS deliberately keeps this at 1 block/CU — 2-block co-residency
// empirically corrupts results (R2/R3/R9/R11/R12 all failed; R4-R8/R10 passed).

template<int NT, class EPI>
__device__ __forceinline__ void gemm8(const u16* A, const u16* W,
                                      int wave, int lane, EPI epi){
  const int g = lane>>4, cc = lane&15;
  const int row = wave*16 + cc;
  bh8 a0 = ldf(&A[row*72 + g*8]);
  bh8 a1 = ldf(&A[row*72 + 32 + g*8]);
  #pragma unroll
  for (int nt=0;nt<NT;nt++){
    bh8 b0 = ldf(&W[(nt*16+cc)*72 + g*8]);
    bh8 b1 = ldf(&W[(nt*16+cc)*72 + 32 + g*8]);
    fx4 acc = {0.f,0.f,0.f,0.f};
    acc = MFMA(a0,b0,acc);
    acc = MFMA(a1,b1,acc);
    epi(nt, wave, acc);
  }
}

template<bool PRE>
__device__ __forceinline__ void stageW(u16* dst, const u16* wsrc, const float* fsrc, int rows){
  if (PRE){
    const int n = rows*72;
    for (int i=threadIdx.x*8; i<n; i+=4096)
      *(bh8*)(dst+i) = *(const bh8*)(wsrc+i);
  } else {
    const int n = rows*64;
    for (int i=threadIdx.x; i<n; i+=512)
      dst[(i>>6)*72 + (i&63)] = f2b(fsrc[i]);
  }
}

// -------- Rodrigues + rod LN phase (verbatim R8, all 512 threads, 4/row) --------
__device__ __forceinline__ void rodrigues_phase(SMem2& s, int t, int tid,
  const float* __restrict__ rod_mix, const float* __restrict__ rod_theta_w,
  const float* __restrict__ rod_theta_b, const float* __restrict__ rod_gen,
  const float* __restrict__ rod_ln_g, const float* __restrict__ rod_ln_b)
{
  const int unit = tid>>2, o = tid&3;          // unit 0..127
  const int b = unit>>5, row = unit&31;
  float nv[16];
  if (row == 0){
    #pragma unroll
    for (int i=0;i<16;i++) nv[i] = s.tokf[b][0][o*16+i];
  } else {
    const int j = row-1;
    const long wj = (long)t*31 + j;
    const float* mixp = rod_mix + wj*16 + o*4;
    const float* thwp = rod_theta_w + wj*32 + o*8;
    const float* genp = rod_gen + wj*16;
    float a = rod_theta_b[wj*4+o];
    #pragma unroll
    for (int c8=0;c8<8;c8++) a += s.joint[b][j][c8]*thwp[c8];
    float sn = sinf(a), c1 = 1.f - cosf(a);
    const float m0 = mixp[0], m1 = mixp[1], m2 = mixp[2], m3 = mixp[3];
    float G[16];
    #pragma unroll
    for (int e=0;e<16;e++) G[e] = genp[e];
    #pragma unroll
    for (int z=0;z<4;z++){
      float fm[4], gf[4], gg[4];
      #pragma unroll
      for (int x=0;x<4;x++)
        fm[x] = m0*s.tokf[b][j][     x*4+z] + m1*s.tokf[b][j][16 + x*4+z]
              + m2*s.tokf[b][j][32 + x*4+z] + m3*s.tokf[b][j][48 + x*4+z];
      #pragma unroll
      for (int x=0;x<4;x++)
        gf[x] = G[x*4+0]*fm[0] + G[x*4+1]*fm[1] + G[x*4+2]*fm[2] + G[x*4+3]*fm[3];
      #pragma unroll
      for (int x=0;x<4;x++)
        gg[x] = G[x*4+0]*gf[0] + G[x*4+1]*gf[1] + G[x*4+2]*gf[2] + G[x*4+3]*gf[3];
      #pragma unroll
      for (int x=0;x<4;x++)
        nv[x*4+z] = fm[x] + sn*gf[x] + c1*gg[x] + s.tokf[b][row][o*16+x*4+z];
    }
  }
  float sum=0.f, ssq=0.f;
  #pragma unroll
  for (int i=0;i<16;i++){ sum+=nv[i]; ssq+=nv[i]*nv[i]; }
  sum += __shfl_xor(sum,1); ssq += __shfl_xor(ssq,1);
  sum += __shfl_xor(sum,2); ssq += __shfl_xor(ssq,2);
  float mean = sum*(1.f/64.f);
  float var  = ssq*(1.f/64.f) - mean*mean;
  float rstd = rsqrtf(var + 1e-5f);
  const float* lng = rod_ln_g + ((long)t*32+row)*64 + o*16;
  const float* lnb = rod_ln_b + ((long)t*32+row)*64 + o*16;
  #pragma unroll
  for (int i=0;i<16;i++)
    nv[i] = (nv[i]-mean)*rstd*lng[i] + lnb[i];
  __syncthreads();   // all reads of old tok complete before overwrite
  #pragma unroll
  for (int i=0;i<16;i++){
    s.tokf[b][row][o*16+i] = nv[i];
    s.tokb[b][row][o*16+i] = f2b(nv[i]);
  }
}

// -------- attention phase (verbatim R8, 8 waves) --------
__device__ __forceinline__ void attn_phase(SMem2& s, int wave, int g, int cc){
  const int b = wave>>1;
  const u16* qb = s.qs + b*32*72;
  const u16* kb = s.kk + b*32*72;
  u16* ob = s.xs + b*32*72;
  bh8 z8 = {0,0,0,0,0,0,0,0};
  #pragma unroll
  for (int hh=0;hh<2;hh++){
    const int h = (wave&1) + 2*hh;
    bh8 qf[2], kf[2];
    #pragma unroll
    for (int it=0;it<2;it++)
      qf[it] = (g<2) ? ldf(&qb[(it*16+cc)*72 + h*16 + g*8]) : z8;
    #pragma unroll
    for (int jt=0;jt<2;jt++)
      kf[jt] = (g<2) ? ldf(&kb[(jt*16+cc)*72 + h*16 + g*8]) : z8;
    fx4 sacc[2][2];
    #pragma unroll
    for (int it=0;it<2;it++)
      #pragma unroll
      for (int jt=0;jt<2;jt++){
        fx4 z = {0.f,0.f,0.f,0.f};
        sacc[it][jt] = MFMA(qf[it], kf[jt], z);  // S[i][j]
      }
    float pn[2][2][4];
    #pragma unroll
    for (int it=0;it<2;it++)
      #pragma unroll
      for (int r=0;r<4;r++){
        float v0 = sacc[it][0][r], v1 = sacc[it][1][r];
        float m = fmaxf(v0,v1);
        #pragma unroll
        for (int msk=1; msk<16; msk<<=1) m = fmaxf(m, __shfl_xor(m,msk));
        float e0 = __expf((v0-m)*0.25f);
        float e1 = __expf((v1-m)*0.25f);
        float sm = e0+e1;
        #pragma unroll
        for (int msk=1; msk<16; msk<<=1) sm += __shfl_xor(sm,msk);
        float inv = 1.f/sm;
        pn[it][0][r]=e0*inv; pn[it][1][r]=e1*inv;
      }
    #pragma unroll
    for (int it=0;it<2;it++)
      #pragma unroll
      for (int jt=0;jt<2;jt++)
        #pragma unroll
        for (int r=0;r<4;r++)
          s.u.p[wave][it*16+g*4+r][jt*16+cc] = f2b(pn[it][jt][r]);
    bh8 vf = ldf(&s.vT[b][h*16+cc][g*8]);
    #pragma unroll
    for (int it=0;it<2;it++){
      bh8 pf = ldf(&s.u.p[wave][it*16+cc][g*8]);
      fx4 z = {0.f,0.f,0.f,0.f};
      fx4 oacc = MFMA(pf, vf, z);
      #pragma unroll
      for (int r=0;r<4;r++)
        ob[(it*16+g*4+r)*72 + h*16+cc] = f2b(oacc[r]);
    }
  }
}

// -------- attn LN phase (verbatim R8) --------
__device__ __forceinline__ void attnln_phase(SMem2& s, int t, int tid,
  const float* __restrict__ attn_ln_g, const float* __restrict__ attn_ln_b)
{
  const int unit = tid>>2, o = tid&3;
  const int b = unit>>5, row = unit&31;
  float v[16];
  #pragma unroll
  for (int i=0;i<16;i++) v[i] = s.tokf[b][row][o*16+i];
  float sum=0.f, ssq=0.f;
  #pragma unroll
  for (int i=0;i<16;i++){ sum+=v[i]; ssq+=v[i]*v[i]; }
  sum += __shfl_xor(sum,1); ssq += __shfl_xor(ssq,1);
  sum += __shfl_xor(sum,2); ssq += __shfl_xor(ssq,2);
  float mean = sum*(1.f/64.f);
  float var  = ssq*(1.f/64.f) - mean*mean;
  float rstd = rsqrtf(var + 1e-5f);
  const float* lg = attn_ln_g + (long)t*64 + o*16;
  const float* lb = attn_ln_b + (long)t*64 + o*16;
  #pragma unroll
  for (int i=0;i<16;i++){
    float ov = (v[i]-mean)*rstd*lg[i] + lb[i];
    s.tokf[b][row][o*16+i] = ov;
    s.tokb[b][row][o*16+i] = f2b(ov);
  }
}

// ================= Main kernel (PRE, folded): 4 batches / 512 threads / 1 block/CU =================
__global__ __launch_bounds__(512,1) void rodri_fold(
  const float* __restrict__ rod_mix, const float* __restrict__ rod_theta_w,
  const float* __restrict__ rod_theta_b, const float* __restrict__ rod_gen,
  const float* __restrict__ rod_ln_g, const float* __restrict__ rod_ln_b,
  const float* __restrict__ jl_w, const float* __restrict__ jl_b,
  const float* __restrict__ attn_ln_g, const float* __restrict__ attn_ln_b,
  const u16* __restrict__ wsw, float* __restrict__ dout)
{
  __shared__ SMem2 s;
  const int tid = threadIdx.x;
  const int wave = tid>>6, lane = tid&63;
  const int g = lane>>4, cc = lane&15;
  const long bb = (long)blockIdx.x*4;

  for (int i=tid;i<4*2048;i+=512){
    int b=i>>11, r=i&2047;
    float v = dout[(bb+b)*2296 + r];
    s.tokf[b][r>>6][r&63] = v;
    s.tokb[b][r>>6][r&63] = f2b(v);
  }
  for (int i=tid;i<4*248;i+=512){
    int b=i/248, r=i-b*248;
    s.joint[b][r>>3][r&7] = dout[(bb+b)*2296 + 2048 + r];
  }
  __syncthreads();

  for (int t=0;t<3;t++){
    rodrigues_phase(s, t, tid, rod_mix, rod_theta_w, rod_theta_b, rod_gen, rod_ln_g, rod_ln_b);
    __syncthreads();

    // joint update
    if (tid < 248){
      int j = tid>>3, c8 = tid&7;
      const float* wrow = jl_w + (((long)t*31 + j)*8 + c8)*64;
      float bias = jl_b[((long)t*31+j)*8 + c8];
      float a0=0.f,a1=0.f,a2=0.f,a3=0.f;
      for (int h=0;h<64;h++){
        float w = wrow[h];
        a0 += w*b2f(s.tokb[0][j+1][h]);
        a1 += w*b2f(s.tokb[1][j+1][h]);
        a2 += w*b2f(s.tokb[2][j+1][h]);
        a3 += w*b2f(s.tokb[3][j+1][h]);
      }
      s.joint[0][j][c8] += a0 + bias;
      s.joint[1][j][c8] += a1 + bias;
      s.joint[2][j][c8] += a2 + bias;
      s.joint[3][j][c8] += a3 + bias;
    }
    __syncthreads();

    // -------- folded qkv: qkv = tok @ Wqp^T + bq'  (A = tokb directly) --------
    stageW<true>(s.u.w, wsw+OFF_QP+(long)t*13824, nullptr, 192);
    __syncthreads();
    {
      const float* bq = (const float*)(wsw + OFF_BQ) + (long)t*192;
      gemm8<12>(&s.tokb[0][0][0], s.u.w, wave, lane,
        [&](int nt,int mtile,const fx4& acc){
          int col = nt*16+cc;
          float bias = bq[col];
          #pragma unroll
          for (int r=0;r<4;r++){
            int rg = mtile*16+g*4+r;
            float v = acc[r]+bias;
            int b = rg>>5, l = rg&31;
            if (col<64)       s.qs[rg*72+col]      = f2b(v);
            else if (col<128) s.kk[rg*72+(col-64)] = f2b(v);
            else              s.vT[b][col-128][l]  = f2b(v);
          }
        });
    }
    __syncthreads();   // all waves done reading u.w before P clobbers it

    attn_phase(s, wave, g, cc);
    __syncthreads();

    // -------- folded output proj: tok += o @ Wop^T + bo' --------
    stageW<true>(s.u.w, wsw+OFF_OP+(long)t*4608, nullptr, 64);
    __syncthreads();
    {
      const float* bo = (const float*)(wsw + OFF_BO) + (long)t*64;
      gemm8<4>(s.xs, s.u.w, wave, lane,
        [&](int nt,int mtile,const fx4& acc){
          int col = nt*16+cc;
          float bias = bo[col];
          #pragma unroll
          for (int r=0;r<4;r++){
            int rg = mtile*16+g*4+r;
            int b = rg>>5, l = rg&31;
            s.tokf[b][l][col] += acc[r] + bias;
          }
        });
    }
    __syncthreads();

    attnln_phase(s, t, tid, attn_ln_g, attn_ln_b);
    __syncthreads();
  } // t

  for (int i=tid;i<4*2048;i+=512){
    int b=i>>11, r=i&2047;
    dout[(bb+b)*2296 + r] = s.tokf[b][r>>6][r&63];
  }
  for (int i=tid;i<4*248;i+=512){
    int b=i/248, r=i-b*248;
    dout[(bb+b)*2296 + 2048 + r] = s.joint[b][r>>3][r&7];
  }
}

// ================= Fallback kernel (non-PRE): R8 proven, unfused =================
__global__ __launch_bounds__(512,1) void rodri_nopre(
  const float* __restrict__ rod_mix, const float* __restrict__ rod_theta_w,
  const float* __restrict__ rod_theta_b, const float* __restrict__ rod_gen,
  const float* __restrict__ rod_ln_g, const float* __restrict__ rod_ln_b,
  const float* __restrict__ jl_w, const float* __restrict__ jl_b,
  const float* __restrict__ proj_in_w, const float* __restrict__ proj_in_b,
  const float* __restrict__ qkv_w, const float* __restrict__ qkv_b,
  const float* __restrict__ attn_out_w, const float* __restrict__ attn_out_b,
  const float* __restrict__ proj_out_w, const float* __restrict__ proj_out_b,
  const float* __restrict__ attn_ln_g, const float* __restrict__ attn_ln_b,
  float* __restrict__ dout)
{
  __shared__ SMem2 s;
  const int tid = threadIdx.x;
  const int wave = tid>>6, lane = tid&63;
  const int g = lane>>4, cc = lane&15;
  const long bb = (long)blockIdx.x*4;

  for (int i=tid;i<4*2048;i+=512){
    int b=i>>11, r=i&2047;
    float v = dout[(bb+b)*2296 + r];
    s.tokf[b][r>>6][r&63] = v;
    s.tokb[b][r>>6][r&63] = f2b(v);
  }
  for (int i=tid;i<4*248;i+=512){
    int b=i/248, r=i-b*248;
    s.joint[b][r>>3][r&7] = dout[(bb+b)*2296 + 2048 + r];
  }
  __syncthreads();

  for (int t=0;t<3;t++){
    rodrigues_phase(s, t, tid, rod_mix, rod_theta_w, rod_theta_b, rod_gen, rod_ln_g, rod_ln_b);
    __syncthreads();

    if (tid < 248){
      int j = tid>>3, c8 = tid&7;
      const float* wrow = jl_w + (((long)t*31 + j)*8 + c8)*64;
      float bias = jl_b[((long)t*31+j)*8 + c8];
      float a0=0.f,a1=0.f,a2=0.f,a3=0.f;
      for (int h=0;h<64;h++){
        float w = wrow[h];
        a0 += w*b2f(s.tokb[0][j+1][h]);
        a1 += w*b2f(s.tokb[1][j+1][h]);
        a2 += w*b2f(s.tokb[2][j+1][h]);
        a3 += w*b2f(s.tokb[3][j+1][h]);
      }
      s.joint[0][j][c8] += a0 + bias;
      s.joint[1][j][c8] += a1 + bias;
      s.joint[2][j][c8] += a2 + bias;
      s.joint[3][j][c8] += a3 + bias;
    }
    __syncthreads();

    stageW<false>(s.u.w, nullptr, proj_in_w+(long)t*4096, 64);
    __syncthreads();
    {
      const float* bp = proj_in_b + (long)t*64;
      gemm8<4>(&s.tokb[0][0][0], s.u.w, wave, lane,
        [&](int nt,int mtile,const fx4& acc){
          int col = nt*16+cc;
          float bias = bp[col];
          #pragma unroll
          for (int r=0;r<4;r++){
            int rg = mtile*16+g*4+r;
            s.xs[rg*72+col] = f2b(acc[r]+bias);
          }
        });
    }
    __syncthreads();

    stageW<false>(s.u.w, nullptr, qkv_w+(long)t*12288, 192);
    __syncthreads();
    {
      const float* bq = qkv_b + (long)t*192;
      gemm8<12>(s.xs, s.u.w, wave, lane,
        [&](int nt,int mtile,const fx4& acc){
          int col = nt*16+cc;
          float bias = bq[col];
          #pragma unroll
          for (int r=0;r<4;r++){
            int rg = mtile*16+g*4+r;
            float v = acc[r]+bias;
            int b = rg>>5, l = rg&31;
            if (col<64)       s.qs[rg*72+col]      = f2b(v);
            else if (col<128) s.kk[rg*72+(col-64)] = f2b(v);
            else              s.vT[b][col-128][l]  = f2b(v);
          }
        });
    }
    __syncthreads();

    attn_phase(s, wave, g, cc);
    __syncthreads();

    stageW<false>(s.u.w, nullptr, attn_out_w+(long)t*4096, 64);
    __syncthreads();
    {
      const float* bo = attn_out_b + (long)t*64;
      gemm8<4>(s.xs, s.u.w, wave, lane,
        [&](int nt,int mtile,const fx4& acc){
          int col = nt*16+cc;
          float bias = bo[col];
          #pragma unroll
          for (int r=0;r<4;r++){
            int rg = mtile*16+g*4+r;
            s.qs[rg*72+col] = f2b(acc[r]+bias);
          }
        });
    }
    __syncthreads();

    stageW<false>(s.u.w, nullptr, proj_out_w+(long)t*4096, 64);
    __syncthreads();
    {
      const float* bp2 = proj_out_b + (long)t*64;
      gemm8<4>(s.qs, s.u.w, wave, lane,
        [&](int nt,int mtile,const fx4& acc){
          int col = nt*16+cc;
          float bias = bp2[col];
          #pragma unroll
          for (int r=0;r<4;r++){
            int rg = mtile*16+g*4+r;
            int b = rg>>5, l = rg&31;
            s.tokf[b][l][col] += acc[r] + bias;
          }
        });
    }
    __syncthreads();

    attnln_phase(s, t, tid, attn_ln_g, attn_ln_b);
    __syncthreads();
  } // t

  for (int i=tid;i<4*2048;i+=512){
    int b=i>>11, r=i&2047;
    dout[(bb+b)*2296 + r] = s.tokf[b][r>>6][r&63];
  }
  for (int i=tid;i<4*248;i+=512){
    int b=i/248, r=i-b*248;
    dout[(bb+b)*2296 + 2048 + r] = s.joint[b][r>>3][r&7];
  }
}

extern "C" void kernel_launch(void* const* d_in, const int* in_sizes, int n_in,
                              void* d_out, int out_size, void* d_ws, size_t ws_size,
                              hipStream_t stream) {
  (void)in_sizes; (void)n_in; (void)out_size;
  float* out = (float*)d_out;
  u16* ws = (u16*)d_ws;
  const bool pre = (ws_size >= (size_t)WS_U16*2);

  if (pre){
    conv_kernel<<<dim3(512), dim3(256), 0, stream>>>(
      (const float*)d_in[1], (const float*)d_in[3], (const float*)d_in[5],
      (const float*)d_in[15], (const float*)d_in[16],
      (const float*)d_in[17], (const float*)d_in[18],
      (const float*)d_in[19], (const float*)d_in[20],
      (const float*)d_in[21], (const float*)d_in[22], ws);
    enc_kernel<true><<<dim3(512), dim3(256), 0, stream>>>(
      (const float*)d_in[0], (const float*)d_in[1], (const float*)d_in[2],
      (const float*)d_in[3], (const float*)d_in[4], (const float*)d_in[5],
      (const float*)d_in[6], ws, out);
    rodri_fold<<<dim3(2048), dim3(512), 0, stream>>>(
      (const float*)d_in[7],  (const float*)d_in[8],  (const float*)d_in[9],
      (const float*)d_in[10], (const float*)d_in[11], (const float*)d_in[12],
      (const float*)d_in[13], (const float*)d_in[14],
      (const float*)d_in[23], (const float*)d_in[24],
      ws, out);
  } else {
    enc_kernel<false><<<dim3(512), dim3(256), 0, stream>>>(
      (const float*)d_in[0], (const float*)d_in[1], (const float*)d_in[2],
      (const float*)d_in[3], (const float*)d_in[4], (const float*)d_in[5],
      (const float*)d_in[6], ws, out);
    rodri_nopre<<<dim3(2048), dim3(512), 0, stream>>>(
      (const float*)d_in[7],  (const float*)d_in[8],  (const float*)d_in[9],
      (const float*)d_in[10], (const float*)d_in[11], (const float*)d_in[12],
      (const float*)d_in[13], (const float*)d_in[14], (const float*)d_in[15],
      (const float*)d_in[16], (const float*)d_in[17], (const float*)d_in[18],
      (const float*)d_in[19], (const float*)d_in[20], (const float*)d_in[21],
      (const float*)d_in[22], (const float*)d_in[23], (const float*)d_in[24],
      out);
  }
}